// Round 4
// baseline (276.326 us; speedup 1.0000x reference)
//
#include <hip/hip_runtime.h>
#include <stdint.h>

#define E 1024
#define S 2048
#define NH 16
#define HD 64

typedef _Float16 f16;
typedef _Float16 f16x4 __attribute__((ext_vector_type(4)));
typedef _Float16 f16x8 __attribute__((ext_vector_type(8)));
typedef __fp16 hv4 __attribute__((ext_vector_type(4)));
typedef float f32x4 __attribute__((ext_vector_type(4)));

__device__ __forceinline__ void async16(const void* g, void* l) {
  __builtin_amdgcn_global_load_lds(
      (const __attribute__((address_space(1))) unsigned int*)g,
      (__attribute__((address_space(3))) unsigned int*)l, 16, 0, 0);
}

// ---------------- conversion kernels ----------------

__global__ __launch_bounds__(256) void cvt_x(const float* __restrict__ x,
                                             f16* __restrict__ xh,
                                             f16* __restrict__ xl) {
  int i = (blockIdx.x * 256 + threadIdx.x) * 4;
  float4 a = *(const float4*)(x + i);
  f16 h0 = (f16)a.x, h1 = (f16)a.y, h2 = (f16)a.z, h3 = (f16)a.w;
  f16x4 hv = {h0, h1, h2, h3};
  f16x4 lv = {(f16)(a.x - (float)h0), (f16)(a.y - (float)h1),
              (f16)(a.z - (float)h2), (f16)(a.w - (float)h3)};
  *(f16x4*)(xh + i) = hv;
  *(f16x4*)(xl + i) = lv;
}

__global__ __launch_bounds__(256) void cvt_w(const float* __restrict__ Wq,
                                             const float* __restrict__ Wk,
                                             const float* __restrict__ Wv,
                                             const float* __restrict__ Wo,
                                             f16* __restrict__ Wh,
                                             f16* __restrict__ Wl) {
  __shared__ float tile[32][33];
  const int z = blockIdx.z;
  const float* W = z == 0 ? Wq : z == 1 ? Wk : z == 2 ? Wv : Wo;
  const int tx = threadIdx.x, ty = threadIdx.y;  // 32 x 8
  const int x0 = blockIdx.x * 32, y0 = blockIdx.y * 32;
#pragma unroll
  for (int i = 0; i < 4; i++)
    tile[ty + i * 8][tx] = W[(size_t)(y0 + ty + i * 8) * E + x0 + tx];
  __syncthreads();
  f16* outh = Wh + (size_t)z * E * E;
  f16* outl = Wl + (size_t)z * E * E;
#pragma unroll
  for (int i = 0; i < 4; i++) {
    float v = tile[tx][ty + i * 8];
    size_t o = (size_t)(x0 + ty + i * 8) * E + (y0 + tx);  // [n][k]
    f16 hi = (f16)v;
    outh[o] = hi;
    if (z < 2) outl[o] = (f16)(v - (float)hi);
  }
}

// ---------------- GEMM mainloop (C = A * B^T, both K-major fp16) ----------------

template <bool SPLIT2>
__device__ __forceinline__ void gemm_mainloop(
    const f16* __restrict__ Ah, const f16* __restrict__ Al,
    const f16* __restrict__ Bh, const f16* __restrict__ Bl, int m0, int n0,
    int K, f16* Ahs, f16* Als, f16* Bhs, f16* Bls, f32x4 acc[4][4]) {
  const int tid = threadIdx.x, lane = tid & 63, wid = tid >> 6;
  const int quad = lane >> 4, c16 = lane & 15;
  const int rA = tid >> 2;
  const int cA = (tid & 3) ^ ((rA >> 1) & 3);
  const size_t gA0 = (size_t)(m0 + rA) * K + cA * 8;
  const size_t gA1 = (size_t)(m0 + 64 + rA) * K + cA * 8;
  const size_t gB0 = (size_t)(n0 + rA) * K + cA * 8;
  const size_t gB1 = (size_t)(n0 + 64 + rA) * K + cA * 8;
  const int l0 = tid * 8, l1 = (256 + tid) * 8;
  int a_off[4], b_off[4];
#pragma unroll
  for (int i = 0; i < 4; i++) {
    int ra = (wid >> 1) * 64 + i * 16 + c16;
    a_off[i] = ra * 32 + ((quad ^ ((ra >> 1) & 3)) << 3);
    int rb = (wid & 1) * 64 + i * 16 + c16;
    b_off[i] = rb * 32 + ((quad ^ ((rb >> 1) & 3)) << 3);
  }
  for (int k0 = 0; k0 < K; k0 += 32) {
    __syncthreads();
    async16(Ah + gA0 + k0, Ahs + l0);
    async16(Ah + gA1 + k0, Ahs + l1);
    async16(Bh + gB0 + k0, Bhs + l0);
    async16(Bh + gB1 + k0, Bhs + l1);
    if constexpr (SPLIT2) {
      async16(Al + gA0 + k0, Als + l0);
      async16(Al + gA1 + k0, Als + l1);
      async16(Bl + gB0 + k0, Bls + l0);
      async16(Bl + gB1 + k0, Bls + l1);
    }
    __syncthreads();
    f16x8 ah[4], bh[4];
#pragma unroll
    for (int i = 0; i < 4; i++) {
      ah[i] = *(const f16x8*)(Ahs + a_off[i]);
      bh[i] = *(const f16x8*)(Bhs + b_off[i]);
    }
    if constexpr (SPLIT2) {
      f16x8 al[4], bl[4];
#pragma unroll
      for (int i = 0; i < 4; i++) {
        al[i] = *(const f16x8*)(Als + a_off[i]);
        bl[i] = *(const f16x8*)(Bls + b_off[i]);
      }
#pragma unroll
      for (int i = 0; i < 4; i++)
#pragma unroll
        for (int j = 0; j < 4; j++) {
          acc[i][j] = __builtin_amdgcn_mfma_f32_16x16x32_f16(ah[i], bh[j], acc[i][j], 0, 0, 0);
          acc[i][j] = __builtin_amdgcn_mfma_f32_16x16x32_f16(ah[i], bl[j], acc[i][j], 0, 0, 0);
          acc[i][j] = __builtin_amdgcn_mfma_f32_16x16x32_f16(al[i], bh[j], acc[i][j], 0, 0, 0);
        }
    } else {
#pragma unroll
      for (int i = 0; i < 4; i++)
#pragma unroll
        for (int j = 0; j < 4; j++)
          acc[i][j] = __builtin_amdgcn_mfma_f32_16x16x32_f16(ah[i], bh[j], acc[i][j], 0, 0, 0);
    }
  }
}

// ---------------- QKV projection ----------------
// z=0: Q (split, prescaled), z=1: K (split, prescaled), z=2: V -> (B,H,D,S)
__global__ __launch_bounds__(256) void qkv_gemm(
    const f16* __restrict__ xh, const f16* __restrict__ xl,
    const f16* __restrict__ Wh, const f16* __restrict__ Wl,
    f16* __restrict__ Qh, f16* __restrict__ Ql, f16* __restrict__ Kh,
    f16* __restrict__ Kl, f16* __restrict__ Vt) {
  __shared__ __align__(16) char smem_raw[36864];
  f16* Ahs = (f16*)smem_raw;
  f16* Als = Ahs + 4096;
  f16* Bhs = Ahs + 8192;
  f16* Bls = Ahs + 12288;
  const int z = blockIdx.z;
  const int m0 = blockIdx.y * 128, n0 = blockIdx.x * 128;
  const f16* Bth = Wh + (size_t)z * E * E;
  const f16* Btl = Wl + (size_t)z * E * E;
  f32x4 acc[4][4];
  const f32x4 zero4 = {0.f, 0.f, 0.f, 0.f};
#pragma unroll
  for (int i = 0; i < 4; i++)
#pragma unroll
    for (int j = 0; j < 4; j++) acc[i][j] = zero4;
  if (z < 2)
    gemm_mainloop<true>(xh, xl, Bth, Btl, m0, n0, E, Ahs, Als, Bhs, Bls, acc);
  else
    gemm_mainloop<false>(xh, nullptr, Bth, nullptr, m0, n0, E, Ahs, Als, Bhs, Bls, acc);
  const int tid = threadIdx.x, lane = tid & 63, wid = tid >> 6;
  const int quad = lane >> 4, c16 = lane & 15;
  __syncthreads();
  f16* vbuf = (f16*)smem_raw + (size_t)wid * 4608;  // 64 rows x 72 stride
  if (z == 2) {
    // transpose wave's 64x64 tile through LDS, store Vt (B,H,D,S) coalesced
#pragma unroll
    for (int i = 0; i < 4; i++)
#pragma unroll
      for (int j = 0; j < 4; j++)
#pragma unroll
        for (int r = 0; r < 4; r++) {
          int sl = i * 16 + quad * 4 + r;
          int dl = j * 16 + c16;
          vbuf[dl * 72 + sl] = (f16)acc[i][j][r];
        }
#pragma unroll
    for (int i2 = 0; i2 < 8; i2++) {
      int dl = i2 * 8 + (lane >> 3);
      int ck = lane & 7;
      f16x8 v8 = *(const f16x8*)(vbuf + dl * 72 + ck * 8);
      int dg = n0 + (wid & 1) * 64 + dl;
      int sg = m0 + (wid >> 1) * 64 + ck * 8;
      int b = sg >> 11, s = sg & (S - 1);
      int h = dg >> 6, d = dg & 63;
      *(f16x8*)(Vt + (((size_t)(b * NH + h) * HD + d) << 11) + s) = v8;
    }
  } else {
    // pack wave's 64x64 (tokens x one head's d) tile, store b128 coalesced
    const int t0 = m0 + (wid >> 1) * 64;
    const int h = (n0 + (wid & 1) * 64) >> 6;
    const float sc = 0.42466090014400953f;  // sqrt(0.125*log2(e))
    f16* dsth = (z == 0) ? Qh : Kh;
    f16* dstl = (z == 0) ? Ql : Kl;
#pragma unroll
    for (int pass = 0; pass < 2; pass++) {
#pragma unroll
      for (int i = 0; i < 4; i++)
#pragma unroll
        for (int j = 0; j < 4; j++)
#pragma unroll
          for (int r = 0; r < 4; r++) {
            float v = acc[i][j][r] * sc;
            f16 hi = (f16)v;
            f16 outv = (pass == 0) ? hi : (f16)(v - (float)hi);
            vbuf[(i * 16 + quad * 4 + r) * 72 + j * 16 + c16] = outv;
          }
      f16* dst = (pass == 0) ? dsth : dstl;
#pragma unroll
      for (int it = 0; it < 8; it++) {
        int row = it * 8 + (lane >> 3);
        int ck = lane & 7;
        f16x8 v8 = *(const f16x8*)(vbuf + row * 72 + ck * 8);
        int tok = t0 + row;
        int b = tok >> 11, s = tok & (S - 1);
        *(f16x8*)(dst + (((size_t)(b * NH + h) * S + s) << 6) + ck * 8) = v8;
      }
    }
  }
}

// ---------------- flash attention (S^T orientation, 64-q-row blocks) ----------------
// 1024 blocks; wave w owns q-rows [16w,16w+16). S^T = K·Q^T (16x16x32, 3-pass
// split); P^T feeds O^T = V^T·P^T (16x16x16) straight from registers.
// Q/K prescaled by sqrt(cf) so logits are already in exp2 units.
__global__ __launch_bounds__(256, 3) void flash(
    const f16* __restrict__ Qh, const f16* __restrict__ Ql,
    const f16* __restrict__ Kh, const f16* __restrict__ Kl,
    const f16* __restrict__ Vt, f16* __restrict__ Ao) {
  __shared__ __align__(16) f16 Khs[2][4096], Kls[2][4096], Vs[2][4096];
  const int tid = threadIdx.x, lane = tid & 63, wid = tid >> 6;
  const int quad = lane >> 4, c16 = lane & 15;
  // XCD swizzle: 4 bh per XCD, heavy q-tiles dispatched first
  const int flat = blockIdx.y * 32 + blockIdx.x;
  const int xcd = flat & 7, slot = flat >> 3;
  const int bh = xcd * 4 + (slot >> 5);
  const int qtile = 31 - (slot & 31);
  const int q0 = qtile * 64;
  const size_t bhoff = (size_t)bh * S * HD;
  const int qbase = wid * 16;
  // Q fragments in registers (B-operand: n=c16 -> q, k=quad*8+j -> d)
  f16x8 qf_h[2], qf_l[2];
#pragma unroll
  for (int ks = 0; ks < 2; ks++) {
    int q = q0 + qbase + c16;
    size_t off = bhoff + (size_t)q * HD + ks * 32 + quad * 8;
    qf_h[ks] = *(const f16x8*)(Qh + off);
    qf_l[ks] = *(const f16x8*)(Ql + off);
  }
  const int niter = qtile + 1;
  const int s0 = tid, s1 = 256 + tid;
  const int r0 = s0 >> 3, cc0 = ((s0 & 7) ^ (r0 & 7)) * 8;
  const int r1 = s1 >> 3, cc1 = ((s1 & 7) ^ (r1 & 7)) * 8;
  auto stage = [&](int it, int b) {
    const size_t kb = bhoff + (size_t)(it * 64) * HD;
    async16(Kh + kb + r0 * HD + cc0, &Khs[b][s0 * 8]);
    async16(Kh + kb + r1 * HD + cc1, &Khs[b][s1 * 8]);
    async16(Kl + kb + r0 * HD + cc0, &Kls[b][s0 * 8]);
    async16(Kl + kb + r1 * HD + cc1, &Kls[b][s1 * 8]);
    const size_t vb = bhoff + (size_t)(it * 64);
    async16(Vt + vb + (size_t)r0 * S + cc0, &Vs[b][s0 * 8]);
    async16(Vt + vb + (size_t)r1 * S + cc1, &Vs[b][s1 * 8]);
  };
  stage(0, 0);
  float mrow = -3.0e38f, lsum = 0.f;
  f32x4 oacc[4];  // O^T: row=quad*4+r -> d, col=c16 -> q
  const f32x4 zero4 = {0.f, 0.f, 0.f, 0.f};
#pragma unroll
  for (int dt = 0; dt < 4; dt++) oacc[dt] = zero4;
  const int qrow = q0 + qbase + c16;
  for (int it = 0; it < niter; ++it) {
    const int cur = it & 1;
    __syncthreads();  // drains prefetch of buf[cur]
    if (it + 1 < niter) stage(it + 1, cur ^ 1);
    const int k0 = it * 64;
    // --- S^T = K . Q^T ---
    f32x4 st[4];
#pragma unroll
    for (int kt = 0; kt < 4; kt++) st[kt] = zero4;
#pragma unroll
    for (int kt = 0; kt < 4; kt++) {
      int rowk = (kt * 16 + c16) * 64;
      int sx = c16 & 7;
      f16x8 kh0 = *(const f16x8*)&Khs[cur][rowk + ((quad ^ sx) << 3)];
      f16x8 kh1 = *(const f16x8*)&Khs[cur][rowk + (((4 + quad) ^ sx) << 3)];
      f16x8 kl0 = *(const f16x8*)&Kls[cur][rowk + ((quad ^ sx) << 3)];
      f16x8 kl1 = *(const f16x8*)&Kls[cur][rowk + (((4 + quad) ^ sx) << 3)];
      st[kt] = __builtin_amdgcn_mfma_f32_16x16x32_f16(kh0, qf_h[0], st[kt], 0, 0, 0);
      st[kt] = __builtin_amdgcn_mfma_f32_16x16x32_f16(kh1, qf_h[1], st[kt], 0, 0, 0);
      st[kt] = __builtin_amdgcn_mfma_f32_16x16x32_f16(kh0, qf_l[0], st[kt], 0, 0, 0);
      st[kt] = __builtin_amdgcn_mfma_f32_16x16x32_f16(kh1, qf_l[1], st[kt], 0, 0, 0);
      st[kt] = __builtin_amdgcn_mfma_f32_16x16x32_f16(kl0, qf_h[0], st[kt], 0, 0, 0);
      st[kt] = __builtin_amdgcn_mfma_f32_16x16x32_f16(kl1, qf_h[1], st[kt], 0, 0, 0);
    }
    // --- online softmax (logits already in exp2 units) ---
    if (it == niter - 1) {
#pragma unroll
      for (int kt = 0; kt < 4; kt++) {
        int kb = k0 + kt * 16 + quad * 4;
#pragma unroll
        for (int r = 0; r < 4; r++)
          if (kb + r > qrow) st[kt][r] = -3.0e38f;
      }
    }
    float mx = -3.0e38f;
#pragma unroll
    for (int kt = 0; kt < 4; kt++) {
      float a = fmaxf(fmaxf(st[kt][0], st[kt][1]), fmaxf(st[kt][2], st[kt][3]));
      mx = fmaxf(mx, a);
    }
    mx = fmaxf(mx, __shfl_xor(mx, 16, 64));
    mx = fmaxf(mx, __shfl_xor(mx, 32, 64));
    float mn = fmaxf(mrow, mx);
    float alpha = __builtin_amdgcn_exp2f(mrow - mn);
    mrow = mn;
    float ls = lsum * alpha;
    hv4 pb[4];
#pragma unroll
    for (int kt = 0; kt < 4; kt++) {
      float p0 = __builtin_amdgcn_exp2f(st[kt][0] - mn);
      float p1 = __builtin_amdgcn_exp2f(st[kt][1] - mn);
      float p2 = __builtin_amdgcn_exp2f(st[kt][2] - mn);
      float p3 = __builtin_amdgcn_exp2f(st[kt][3] - mn);
      ls += (p0 + p1) + (p2 + p3);
      hv4 pv = {(__fp16)p0, (__fp16)p1, (__fp16)p2, (__fp16)p3};
      pb[kt] = pv;
    }
    lsum = ls;
#pragma unroll
    for (int dt = 0; dt < 4; dt++) {
      oacc[dt][0] *= alpha;
      oacc[dt][1] *= alpha;
      oacc[dt][2] *= alpha;
      oacc[dt][3] *= alpha;
    }
    // --- O^T += V^T . P^T ---
#pragma unroll
    for (int kt = 0; kt < 4; kt++) {
#pragma unroll
      for (int dt = 0; dt < 4; dt++) {
        int rowd = dt * 16 + c16;
        int cidx = (kt * 2 + (quad >> 1)) ^ (rowd & 7);
        hv4 vf = *(const hv4*)&Vs[cur][rowd * 64 + (cidx << 3) + (quad & 1) * 4];
        oacc[dt] = __builtin_amdgcn_mfma_f32_16x16x16f16(vf, pb[kt], oacc[dt], 0, 0, 0);
      }
    }
  }
  // --- epilogue ---
  const int bb = bh >> 4, hh = bh & 15;
  float l = lsum;
  l += __shfl_xor(l, 16, 64);
  l += __shfl_xor(l, 32, 64);
  float iv = 1.0f / l;
  const int q = q0 + qbase + c16;
#pragma unroll
  for (int dt = 0; dt < 4; dt++) {
    f16x4 ov = {(f16)(oacc[dt][0] * iv), (f16)(oacc[dt][1] * iv),
                (f16)(oacc[dt][2] * iv), (f16)(oacc[dt][3] * iv)};
    *(f16x4*)(Ao + ((size_t)(bb * S + q)) * E + hh * 64 + dt * 16 + quad * 4) = ov;
  }
}

// ---------------- output projection ----------------
__global__ __launch_bounds__(256) void out_gemm(const f16* __restrict__ Ao,
                                                const f16* __restrict__ Wo,
                                                float* __restrict__ Cout) {
  __shared__ __align__(16) f16 Ahs[4096], Bhs[4096];
  const int m0 = blockIdx.y * 128, n0 = blockIdx.x * 128;
  f32x4 acc[4][4];
  const f32x4 zero4 = {0.f, 0.f, 0.f, 0.f};
#pragma unroll
  for (int i = 0; i < 4; i++)
#pragma unroll
    for (int j = 0; j < 4; j++) acc[i][j] = zero4;
  gemm_mainloop<false>(Ao, nullptr, Wo, nullptr, m0, n0, E, Ahs, nullptr, Bhs, nullptr, acc);
  const int lane = threadIdx.x & 63, wid = threadIdx.x >> 6;
  const int quad = lane >> 4, c16 = lane & 15;
#pragma unroll
  for (int i = 0; i < 4; i++)
#pragma unroll
    for (int j = 0; j < 4; j++)
#pragma unroll
      for (int r = 0; r < 4; r++) {
        int row = m0 + (wid >> 1) * 64 + i * 16 + quad * 4 + r;
        int col = n0 + (wid & 1) * 64 + j * 16 + c16;
        Cout[(size_t)row * E + col] = acc[i][j][r];
      }
}

extern "C" void kernel_launch(void* const* d_in, const int* in_sizes, int n_in,
                              void* d_out, int out_size, void* d_ws,
                              size_t ws_size, hipStream_t stream) {
  const float* x = (const float*)d_in[0];
  const float* Wq = (const float*)d_in[1];
  const float* Wk = (const float*)d_in[2];
  const float* Wv = (const float*)d_in[3];
  const float* Wo = (const float*)d_in[4];
  char* ws = (char*)d_ws;
  const size_t MB = (size_t)1 << 20;
  f16* xh = (f16*)(ws + 0 * MB);
  f16* xl = (f16*)(ws + 8 * MB);
  f16* Wh = (f16*)(ws + 16 * MB);
  f16* Wl = (f16*)(ws + 24 * MB);
  f16* Qh = (f16*)(ws + 28 * MB);
  f16* Ql = (f16*)(ws + 36 * MB);
  f16* Kh = (f16*)(ws + 44 * MB);
  f16* Kl = (f16*)(ws + 52 * MB);
  f16* Vt = (f16*)(ws + 60 * MB);
  f16* Ao = (f16*)(ws + 68 * MB);
  cvt_x<<<4096, 256, 0, stream>>>(x, xh, xl);
  cvt_w<<<dim3(32, 32, 4), dim3(32, 8), 0, stream>>>(Wq, Wk, Wv, Wo, Wh, Wl);
  qkv_gemm<<<dim3(8, 32, 3), 256, 0, stream>>>(xh, xl, Wh, Wl, Qh, Ql, Kh, Kl, Vt);
  flash<<<dim3(32, 32), 256, 0, stream>>>(Qh, Ql, Kh, Kl, Vt, Ao);
  out_gemm<<<dim3(8, 32), 256, 0, stream>>>(Ao, Wh + (size_t)3 * E * E, (float*)d_out);
}

// Round 5
// 241.363 us; speedup vs baseline: 1.1449x; 1.1449x over previous
//
#include <hip/hip_runtime.h>
#include <stdint.h>

#define E 1024
#define S 2048
#define NH 16
#define HD 64

typedef _Float16 f16;
typedef _Float16 f16x4 __attribute__((ext_vector_type(4)));
typedef _Float16 f16x8 __attribute__((ext_vector_type(8)));
typedef __fp16 hv4 __attribute__((ext_vector_type(4)));
typedef float f32x4 __attribute__((ext_vector_type(4)));

__device__ __forceinline__ void async16(const void* g, void* l) {
  __builtin_amdgcn_global_load_lds(
      (const __attribute__((address_space(1))) unsigned int*)g,
      (__attribute__((address_space(3))) unsigned int*)l, 16, 0, 0);
}

// ---------------- fused conversion kernel ----------------
// z<4: transpose W_z -> Wh/Wl (N-major);  z==4: split x -> xh/xl
__global__ __launch_bounds__(256) void cvt_all(
    const float* __restrict__ x, const float* __restrict__ Wq,
    const float* __restrict__ Wk, const float* __restrict__ Wv,
    const float* __restrict__ Wo, f16* __restrict__ xh, f16* __restrict__ xl,
    f16* __restrict__ Wh, f16* __restrict__ Wl) {
  const int z = blockIdx.z;
  const int tid = threadIdx.x;
  if (z == 4) {
    int base = ((blockIdx.y * 32 + blockIdx.x) * 256 + tid) * 16;
#pragma unroll
    for (int u = 0; u < 4; u++) {
      int i = base + u * 4;
      float4 a = *(const float4*)(x + i);
      f16 h0 = (f16)a.x, h1 = (f16)a.y, h2 = (f16)a.z, h3 = (f16)a.w;
      f16x4 hv = {h0, h1, h2, h3};
      f16x4 lv = {(f16)(a.x - (float)h0), (f16)(a.y - (float)h1),
                  (f16)(a.z - (float)h2), (f16)(a.w - (float)h3)};
      *(f16x4*)(xh + i) = hv;
      *(f16x4*)(xl + i) = lv;
    }
    return;
  }
  __shared__ float tile[32][33];
  const float* W = z == 0 ? Wq : z == 1 ? Wk : z == 2 ? Wv : Wo;
  const int tx = tid & 31, ty = tid >> 5;  // 32 x 8
  const int x0 = blockIdx.x * 32, y0 = blockIdx.y * 32;
#pragma unroll
  for (int i = 0; i < 4; i++)
    tile[ty + i * 8][tx] = W[(size_t)(y0 + ty + i * 8) * E + x0 + tx];
  __syncthreads();
  f16* outh = Wh + (size_t)z * E * E;
  f16* outl = Wl + (size_t)z * E * E;
#pragma unroll
  for (int i = 0; i < 4; i++) {
    float v = tile[tx][ty + i * 8];
    size_t o = (size_t)(x0 + ty + i * 8) * E + (y0 + tx);  // [n][k]
    f16 hi = (f16)v;
    outh[o] = hi;
    if (z < 2) outl[o] = (f16)(v - (float)hi);
  }
}

// ---------------- GEMM mainloop (C = A * B^T, both K-major fp16) ----------------
// 128x128 tile, BK=32, 4 waves each 64x64.

template <bool SPLIT2>
__device__ __forceinline__ void gemm_mainloop(
    const f16* __restrict__ Ah, const f16* __restrict__ Al,
    const f16* __restrict__ Bh, const f16* __restrict__ Bl, int m0, int n0,
    int K, f16* Ahs, f16* Als, f16* Bhs, f16* Bls, f32x4 acc[4][4]) {
  const int tid = threadIdx.x, lane = tid & 63, wid = tid >> 6;
  const int quad = lane >> 4, c16 = lane & 15;
  const int rA = tid >> 2;
  const int cA = (tid & 3) ^ ((rA >> 1) & 3);
  const size_t gA0 = (size_t)(m0 + rA) * K + cA * 8;
  const size_t gA1 = (size_t)(m0 + 64 + rA) * K + cA * 8;
  const size_t gB0 = (size_t)(n0 + rA) * K + cA * 8;
  const size_t gB1 = (size_t)(n0 + 64 + rA) * K + cA * 8;
  const int l0 = tid * 8, l1 = (256 + tid) * 8;
  int a_off[4], b_off[4];
#pragma unroll
  for (int i = 0; i < 4; i++) {
    int ra = (wid >> 1) * 64 + i * 16 + c16;
    a_off[i] = ra * 32 + ((quad ^ ((ra >> 1) & 3)) << 3);
    int rb = (wid & 1) * 64 + i * 16 + c16;
    b_off[i] = rb * 32 + ((quad ^ ((rb >> 1) & 3)) << 3);
  }
  for (int k0 = 0; k0 < K; k0 += 32) {
    __syncthreads();
    async16(Ah + gA0 + k0, Ahs + l0);
    async16(Ah + gA1 + k0, Ahs + l1);
    async16(Bh + gB0 + k0, Bhs + l0);
    async16(Bh + gB1 + k0, Bhs + l1);
    if constexpr (SPLIT2) {
      async16(Al + gA0 + k0, Als + l0);
      async16(Al + gA1 + k0, Als + l1);
      async16(Bl + gB0 + k0, Bls + l0);
      async16(Bl + gB1 + k0, Bls + l1);
    }
    __syncthreads();
    f16x8 ah[4], bh[4];
#pragma unroll
    for (int i = 0; i < 4; i++) {
      ah[i] = *(const f16x8*)(Ahs + a_off[i]);
      bh[i] = *(const f16x8*)(Bhs + b_off[i]);
    }
    if constexpr (SPLIT2) {
      f16x8 al[4], bl[4];
#pragma unroll
      for (int i = 0; i < 4; i++) {
        al[i] = *(const f16x8*)(Als + a_off[i]);
        bl[i] = *(const f16x8*)(Bls + b_off[i]);
      }
#pragma unroll
      for (int i = 0; i < 4; i++)
#pragma unroll
        for (int j = 0; j < 4; j++) {
          acc[i][j] = __builtin_amdgcn_mfma_f32_16x16x32_f16(ah[i], bh[j], acc[i][j], 0, 0, 0);
          acc[i][j] = __builtin_amdgcn_mfma_f32_16x16x32_f16(ah[i], bl[j], acc[i][j], 0, 0, 0);
          acc[i][j] = __builtin_amdgcn_mfma_f32_16x16x32_f16(al[i], bh[j], acc[i][j], 0, 0, 0);
        }
    } else {
#pragma unroll
      for (int i = 0; i < 4; i++)
#pragma unroll
        for (int j = 0; j < 4; j++)
          acc[i][j] = __builtin_amdgcn_mfma_f32_16x16x32_f16(ah[i], bh[j], acc[i][j], 0, 0, 0);
    }
  }
}

// ---------------- QKV projection ----------------
// z=0: Q (split, prescaled), z=1: K (split, prescaled), z=2: V -> (B,H,D,S)
__global__ __launch_bounds__(256) void qkv_gemm(
    const f16* __restrict__ xh, const f16* __restrict__ xl,
    const f16* __restrict__ Wh, const f16* __restrict__ Wl,
    f16* __restrict__ Qh, f16* __restrict__ Ql, f16* __restrict__ Kh,
    f16* __restrict__ Kl, f16* __restrict__ Vt) {
  __shared__ __align__(16) char smem_raw[36864];
  f16* Ahs = (f16*)smem_raw;
  f16* Als = Ahs + 4096;
  f16* Bhs = Ahs + 8192;
  f16* Bls = Ahs + 12288;
  const int z = blockIdx.z;
  const int m0 = blockIdx.y * 128, n0 = blockIdx.x * 128;
  const f16* Bth = Wh + (size_t)z * E * E;
  const f16* Btl = Wl + (size_t)z * E * E;
  f32x4 acc[4][4];
  const f32x4 zero4 = {0.f, 0.f, 0.f, 0.f};
#pragma unroll
  for (int i = 0; i < 4; i++)
#pragma unroll
    for (int j = 0; j < 4; j++) acc[i][j] = zero4;
  if (z < 2)
    gemm_mainloop<true>(xh, xl, Bth, Btl, m0, n0, E, Ahs, Als, Bhs, Bls, acc);
  else
    gemm_mainloop<false>(xh, nullptr, Bth, nullptr, m0, n0, E, Ahs, Als, Bhs, Bls, acc);
  const int tid = threadIdx.x, lane = tid & 63, wid = tid >> 6;
  const int quad = lane >> 4, c16 = lane & 15;
  if (z == 2) {
    // transpose wave's 64x64 tile through LDS, store Vt (B,H,D,S) coalesced
    __syncthreads();
    f16* vbuf = (f16*)smem_raw + (size_t)wid * 4608;  // 64 rows x 72 stride
#pragma unroll
    for (int i = 0; i < 4; i++)
#pragma unroll
      for (int j = 0; j < 4; j++)
#pragma unroll
        for (int r = 0; r < 4; r++) {
          int sl = i * 16 + quad * 4 + r;
          int dl = j * 16 + c16;
          vbuf[dl * 72 + sl] = (f16)acc[i][j][r];
        }
#pragma unroll
    for (int i2 = 0; i2 < 8; i2++) {
      int dl = i2 * 8 + (lane >> 3);
      int ck = lane & 7;
      f16x8 v8 = *(const f16x8*)(vbuf + dl * 72 + ck * 8);
      int dg = n0 + (wid & 1) * 64 + dl;
      int sg = m0 + (wid >> 1) * 64 + ck * 8;
      int b = sg >> 11, s = sg & (S - 1);
      int h = dg >> 6, d = dg & 63;
      *(f16x8*)(Vt + (((size_t)(b * NH + h) * HD + d) << 11) + s) = v8;
    }
  } else {
    // scalar split stores (round-3 form: low VGPR pressure beats b128 stores)
    const float sc = 0.42466090014400953f;  // sqrt(0.125*log2(e))
#pragma unroll
    for (int i = 0; i < 4; i++)
#pragma unroll
      for (int j = 0; j < 4; j++)
#pragma unroll
        for (int r = 0; r < 4; r++) {
          int row = m0 + (wid >> 1) * 64 + i * 16 + quad * 4 + r;  // token
          int col = n0 + (wid & 1) * 64 + j * 16 + c16;            // embed idx
          int b = row >> 11, s = row & (S - 1);
          int h = col >> 6, d = col & 63;
          float v = acc[i][j][r] * sc;
          size_t idx = (((size_t)(b * NH + h) * S + s) << 6) + d;
          f16 hi = (f16)v;
          f16 lo = (f16)(v - (float)hi);
          if (z == 0) { Qh[idx] = hi; Ql[idx] = lo; }
          else        { Kh[idx] = hi; Kl[idx] = lo; }
        }
  }
}

// ---------------- flash attention (S^T orientation, 64-q-row blocks) ----------------
__global__ __launch_bounds__(256, 3) void flash(
    const f16* __restrict__ Qh, const f16* __restrict__ Ql,
    const f16* __restrict__ Kh, const f16* __restrict__ Kl,
    const f16* __restrict__ Vt, f16* __restrict__ Ao) {
  __shared__ __align__(16) f16 Khs[2][4096], Kls[2][4096], Vs[2][4096];
  const int tid = threadIdx.x, lane = tid & 63, wid = tid >> 6;
  const int quad = lane >> 4, c16 = lane & 15;
  // XCD swizzle: 4 bh per XCD, heavy q-tiles dispatched first
  const int flat = blockIdx.y * 32 + blockIdx.x;
  const int xcd = flat & 7, slot = flat >> 3;
  const int bh = xcd * 4 + (slot >> 5);
  const int qtile = 31 - (slot & 31);
  const int q0 = qtile * 64;
  const size_t bhoff = (size_t)bh * S * HD;
  const int qbase = wid * 16;
  f16x8 qf_h[2], qf_l[2];
#pragma unroll
  for (int ks = 0; ks < 2; ks++) {
    int q = q0 + qbase + c16;
    size_t off = bhoff + (size_t)q * HD + ks * 32 + quad * 8;
    qf_h[ks] = *(const f16x8*)(Qh + off);
    qf_l[ks] = *(const f16x8*)(Ql + off);
  }
  const int niter = qtile + 1;
  const int s0 = tid, s1 = 256 + tid;
  const int r0 = s0 >> 3, cc0 = ((s0 & 7) ^ (r0 & 7)) * 8;
  const int r1 = s1 >> 3, cc1 = ((s1 & 7) ^ (r1 & 7)) * 8;
  auto stage = [&](int it, int b) {
    const size_t kb = bhoff + (size_t)(it * 64) * HD;
    async16(Kh + kb + r0 * HD + cc0, &Khs[b][s0 * 8]);
    async16(Kh + kb + r1 * HD + cc1, &Khs[b][s1 * 8]);
    async16(Kl + kb + r0 * HD + cc0, &Kls[b][s0 * 8]);
    async16(Kl + kb + r1 * HD + cc1, &Kls[b][s1 * 8]);
    const size_t vb = bhoff + (size_t)(it * 64);
    async16(Vt + vb + (size_t)r0 * S + cc0, &Vs[b][s0 * 8]);
    async16(Vt + vb + (size_t)r1 * S + cc1, &Vs[b][s1 * 8]);
  };
  stage(0, 0);
  float mrow = -3.0e38f, lsum = 0.f;
  f32x4 oacc[4];  // O^T: row=quad*4+r -> d, col=c16 -> q
  const f32x4 zero4 = {0.f, 0.f, 0.f, 0.f};
#pragma unroll
  for (int dt = 0; dt < 4; dt++) oacc[dt] = zero4;
  const int qrow = q0 + qbase + c16;
  for (int it = 0; it < niter; ++it) {
    const int cur = it & 1;
    __syncthreads();  // drains prefetch of buf[cur]
    if (it + 1 < niter) stage(it + 1, cur ^ 1);
    const int k0 = it * 64;
    // --- S^T = K . Q^T ---
    f32x4 st[4];
#pragma unroll
    for (int kt = 0; kt < 4; kt++) st[kt] = zero4;
#pragma unroll
    for (int kt = 0; kt < 4; kt++) {
      int rowk = (kt * 16 + c16) * 64;
      int sx = c16 & 7;
      f16x8 kh0 = *(const f16x8*)&Khs[cur][rowk + ((quad ^ sx) << 3)];
      f16x8 kh1 = *(const f16x8*)&Khs[cur][rowk + (((4 + quad) ^ sx) << 3)];
      f16x8 kl0 = *(const f16x8*)&Kls[cur][rowk + ((quad ^ sx) << 3)];
      f16x8 kl1 = *(const f16x8*)&Kls[cur][rowk + (((4 + quad) ^ sx) << 3)];
      st[kt] = __builtin_amdgcn_mfma_f32_16x16x32_f16(kh0, qf_h[0], st[kt], 0, 0, 0);
      st[kt] = __builtin_amdgcn_mfma_f32_16x16x32_f16(kh1, qf_h[1], st[kt], 0, 0, 0);
      st[kt] = __builtin_amdgcn_mfma_f32_16x16x32_f16(kh0, qf_l[0], st[kt], 0, 0, 0);
      st[kt] = __builtin_amdgcn_mfma_f32_16x16x32_f16(kh1, qf_l[1], st[kt], 0, 0, 0);
      st[kt] = __builtin_amdgcn_mfma_f32_16x16x32_f16(kl0, qf_h[0], st[kt], 0, 0, 0);
      st[kt] = __builtin_amdgcn_mfma_f32_16x16x32_f16(kl1, qf_h[1], st[kt], 0, 0, 0);
    }
    // --- online softmax (logits already in exp2 units) ---
    if (it == niter - 1) {
#pragma unroll
      for (int kt = 0; kt < 4; kt++) {
        int kb = k0 + kt * 16 + quad * 4;
#pragma unroll
        for (int r = 0; r < 4; r++)
          if (kb + r > qrow) st[kt][r] = -3.0e38f;
      }
    }
    float mx = -3.0e38f;
#pragma unroll
    for (int kt = 0; kt < 4; kt++) {
      float a = fmaxf(fmaxf(st[kt][0], st[kt][1]), fmaxf(st[kt][2], st[kt][3]));
      mx = fmaxf(mx, a);
    }
    mx = fmaxf(mx, __shfl_xor(mx, 16, 64));
    mx = fmaxf(mx, __shfl_xor(mx, 32, 64));
    float mn = fmaxf(mrow, mx);
    float alpha = __builtin_amdgcn_exp2f(mrow - mn);
    mrow = mn;
    float ls = lsum * alpha;
    hv4 pb[4];
#pragma unroll
    for (int kt = 0; kt < 4; kt++) {
      float p0 = __builtin_amdgcn_exp2f(st[kt][0] - mn);
      float p1 = __builtin_amdgcn_exp2f(st[kt][1] - mn);
      float p2 = __builtin_amdgcn_exp2f(st[kt][2] - mn);
      float p3 = __builtin_amdgcn_exp2f(st[kt][3] - mn);
      ls += (p0 + p1) + (p2 + p3);
      hv4 pv = {(__fp16)p0, (__fp16)p1, (__fp16)p2, (__fp16)p3};
      pb[kt] = pv;
    }
    lsum = ls;
#pragma unroll
    for (int dt = 0; dt < 4; dt++) {
      oacc[dt][0] *= alpha;
      oacc[dt][1] *= alpha;
      oacc[dt][2] *= alpha;
      oacc[dt][3] *= alpha;
    }
    // --- O^T += V^T . P^T ---
#pragma unroll
    for (int kt = 0; kt < 4; kt++) {
#pragma unroll
      for (int dt = 0; dt < 4; dt++) {
        int rowd = dt * 16 + c16;
        int cidx = (kt * 2 + (quad >> 1)) ^ (rowd & 7);
        hv4 vf = *(const hv4*)&Vs[cur][rowd * 64 + (cidx << 3) + (quad & 1) * 4];
        oacc[dt] = __builtin_amdgcn_mfma_f32_16x16x16f16(vf, pb[kt], oacc[dt], 0, 0, 0);
      }
    }
  }
  // --- epilogue ---
  const int bb = bh >> 4, hh = bh & 15;
  float l = lsum;
  l += __shfl_xor(l, 16, 64);
  l += __shfl_xor(l, 32, 64);
  float iv = 1.0f / l;
  const int q = q0 + qbase + c16;
#pragma unroll
  for (int dt = 0; dt < 4; dt++) {
    f16x4 ov = {(f16)(oacc[dt][0] * iv), (f16)(oacc[dt][1] * iv),
                (f16)(oacc[dt][2] * iv), (f16)(oacc[dt][3] * iv)};
    *(f16x4*)(Ao + ((size_t)(bb * S + q)) * E + hh * 64 + dt * 16 + quad * 4) = ov;
  }
}

// ---------------- output projection (64x128 tiles, 512 blocks) ----------------
__global__ __launch_bounds__(256) void out_gemm(const f16* __restrict__ Ao,
                                                const f16* __restrict__ Wo,
                                                float* __restrict__ Cout) {
  __shared__ __align__(16) f16 Ahs[2048], Bhs[4096];
  const int tid = threadIdx.x, lane = tid & 63, wid = tid >> 6;
  const int quad = lane >> 4, c16 = lane & 15;
  const int m0 = blockIdx.y * 64, n0 = blockIdx.x * 128;
  f32x4 acc[4][2];
  const f32x4 zero4 = {0.f, 0.f, 0.f, 0.f};
#pragma unroll
  for (int i = 0; i < 4; i++)
#pragma unroll
    for (int j = 0; j < 2; j++) acc[i][j] = zero4;
  // staging indices: A 64x32 (1 ld), B 128x32 (2 ld)
  const int rA = tid >> 2;
  const int cA = (tid & 3) ^ ((rA >> 1) & 3);
  const size_t gA0 = (size_t)(m0 + rA) * E + cA * 8;
  const size_t gB0 = (size_t)(n0 + rA) * E + cA * 8;
  const size_t gB1 = (size_t)(n0 + 64 + rA) * E + cA * 8;
  const int l0 = tid * 8, l1 = (256 + tid) * 8;
  int a_off[4], b_off[2];
#pragma unroll
  for (int i = 0; i < 4; i++) {
    int ra = i * 16 + c16;
    a_off[i] = ra * 32 + ((quad ^ ((ra >> 1) & 3)) << 3);
  }
#pragma unroll
  for (int j = 0; j < 2; j++) {
    int rb = wid * 32 + j * 16 + c16;
    b_off[j] = rb * 32 + ((quad ^ ((rb >> 1) & 3)) << 3);
  }
  for (int k0 = 0; k0 < E; k0 += 32) {
    __syncthreads();
    async16(Ao + gA0 + k0, Ahs + l0);
    async16(Wo + gB0 + k0, Bhs + l0);
    async16(Wo + gB1 + k0, Bhs + l1);
    __syncthreads();
    f16x8 ah[4], bh[2];
#pragma unroll
    for (int i = 0; i < 4; i++) ah[i] = *(const f16x8*)(Ahs + a_off[i]);
#pragma unroll
    for (int j = 0; j < 2; j++) bh[j] = *(const f16x8*)(Bhs + b_off[j]);
#pragma unroll
    for (int i = 0; i < 4; i++)
#pragma unroll
      for (int j = 0; j < 2; j++)
        acc[i][j] = __builtin_amdgcn_mfma_f32_16x16x32_f16(ah[i], bh[j], acc[i][j], 0, 0, 0);
  }
#pragma unroll
  for (int i = 0; i < 4; i++)
#pragma unroll
    for (int j = 0; j < 2; j++)
#pragma unroll
      for (int r = 0; r < 4; r++) {
        int row = m0 + i * 16 + quad * 4 + r;
        int col = n0 + wid * 32 + j * 16 + c16;
        Cout[(size_t)row * E + col] = acc[i][j][r];
      }
}

extern "C" void kernel_launch(void* const* d_in, const int* in_sizes, int n_in,
                              void* d_out, int out_size, void* d_ws,
                              size_t ws_size, hipStream_t stream) {
  const float* x = (const float*)d_in[0];
  const float* Wq = (const float*)d_in[1];
  const float* Wk = (const float*)d_in[2];
  const float* Wv = (const float*)d_in[3];
  const float* Wo = (const float*)d_in[4];
  char* ws = (char*)d_ws;
  const size_t MB = (size_t)1 << 20;
  f16* xh = (f16*)(ws + 0 * MB);
  f16* xl = (f16*)(ws + 8 * MB);
  f16* Wh = (f16*)(ws + 16 * MB);
  f16* Wl = (f16*)(ws + 24 * MB);
  f16* Qh = (f16*)(ws + 28 * MB);
  f16* Ql = (f16*)(ws + 36 * MB);
  f16* Kh = (f16*)(ws + 44 * MB);
  f16* Kl = (f16*)(ws + 52 * MB);
  f16* Vt = (f16*)(ws + 60 * MB);
  f16* Ao = (f16*)(ws + 68 * MB);
  cvt_all<<<dim3(32, 32, 5), 256, 0, stream>>>(x, Wq, Wk, Wv, Wo, xh, xl, Wh, Wl);
  qkv_gemm<<<dim3(8, 32, 3), 256, 0, stream>>>(xh, xl, Wh, Wl, Qh, Ql, Kh, Kl, Vt);
  flash<<<dim3(32, 32), 256, 0, stream>>>(Qh, Ql, Kh, Kl, Vt, Ao);
  out_gemm<<<dim3(8, 64), 256, 0, stream>>>(Ao, Wh + (size_t)3 * E * E, (float*)d_out);
}

// Round 6
// 236.398 us; speedup vs baseline: 1.1689x; 1.0210x over previous
//
#include <hip/hip_runtime.h>
#include <stdint.h>

#define E 1024
#define S 2048
#define NH 16
#define HD 64

typedef _Float16 f16;
typedef _Float16 f16x4 __attribute__((ext_vector_type(4)));
typedef _Float16 f16x8 __attribute__((ext_vector_type(8)));
typedef __fp16 hv4 __attribute__((ext_vector_type(4)));
typedef float f32x4 __attribute__((ext_vector_type(4)));

__device__ __forceinline__ void async16(const void* g, void* l) {
  __builtin_amdgcn_global_load_lds(
      (const __attribute__((address_space(1))) unsigned int*)g,
      (__attribute__((address_space(3))) unsigned int*)l, 16, 0, 0);
}

// ---------------- fused conversion kernel ----------------
// z<4: transpose W_z -> Wh/Wl (N-major);  z==4: split x -> xh/xl
__global__ __launch_bounds__(256) void cvt_all(
    const float* __restrict__ x, const float* __restrict__ Wq,
    const float* __restrict__ Wk, const float* __restrict__ Wv,
    const float* __restrict__ Wo, f16* __restrict__ xh, f16* __restrict__ xl,
    f16* __restrict__ Wh, f16* __restrict__ Wl) {
  const int z = blockIdx.z;
  const int tid = threadIdx.x;
  if (z == 4) {
    int base = ((blockIdx.y * 32 + blockIdx.x) * 256 + tid) * 16;
#pragma unroll
    for (int u = 0; u < 4; u++) {
      int i = base + u * 4;
      float4 a = *(const float4*)(x + i);
      f16 h0 = (f16)a.x, h1 = (f16)a.y, h2 = (f16)a.z, h3 = (f16)a.w;
      f16x4 hv = {h0, h1, h2, h3};
      f16x4 lv = {(f16)(a.x - (float)h0), (f16)(a.y - (float)h1),
                  (f16)(a.z - (float)h2), (f16)(a.w - (float)h3)};
      *(f16x4*)(xh + i) = hv;
      *(f16x4*)(xl + i) = lv;
    }
    return;
  }
  __shared__ float tile[32][33];
  const float* W = z == 0 ? Wq : z == 1 ? Wk : z == 2 ? Wv : Wo;
  const int tx = tid & 31, ty = tid >> 5;  // 32 x 8
  const int x0 = blockIdx.x * 32, y0 = blockIdx.y * 32;
#pragma unroll
  for (int i = 0; i < 4; i++)
    tile[ty + i * 8][tx] = W[(size_t)(y0 + ty + i * 8) * E + x0 + tx];
  __syncthreads();
  f16* outh = Wh + (size_t)z * E * E;
  f16* outl = Wl + (size_t)z * E * E;
#pragma unroll
  for (int i = 0; i < 4; i++) {
    float v = tile[tx][ty + i * 8];
    size_t o = (size_t)(x0 + ty + i * 8) * E + (y0 + tx);  // [n][k]
    f16 hi = (f16)v;
    outh[o] = hi;
    if (z < 2) outl[o] = (f16)(v - (float)hi);
  }
}

// ------- GEMM mainloop (C = A * B^T, both K-major fp16), double-buffered -------
// 128x128 tile, BK=32, 4 waves each 64x64. One barrier per K-iter; prefetch of
// tile k+1 issued right after the barrier, drained by the NEXT barrier (aged).

template <bool SPLIT2>
__device__ __forceinline__ void gemm_mainloop(
    const f16* __restrict__ Ah, const f16* __restrict__ Al,
    const f16* __restrict__ Bh, const f16* __restrict__ Bl, int m0, int n0,
    int K, f16* Ahs, f16* Als, f16* Bhs, f16* Bls, f32x4 acc[4][4]) {
  const int tid = threadIdx.x, lane = tid & 63, wid = tid >> 6;
  const int quad = lane >> 4, c16 = lane & 15;
  const int rA = tid >> 2;
  const int cA = (tid & 3) ^ ((rA >> 1) & 3);
  const size_t gA0 = (size_t)(m0 + rA) * K + cA * 8;
  const size_t gA1 = (size_t)(m0 + 64 + rA) * K + cA * 8;
  const size_t gB0 = (size_t)(n0 + rA) * K + cA * 8;
  const size_t gB1 = (size_t)(n0 + 64 + rA) * K + cA * 8;
  const int l0 = tid * 8, l1 = (256 + tid) * 8;
  int a_off[4], b_off[4];
#pragma unroll
  for (int i = 0; i < 4; i++) {
    int ra = (wid >> 1) * 64 + i * 16 + c16;
    a_off[i] = ra * 32 + ((quad ^ ((ra >> 1) & 3)) << 3);
    int rb = (wid & 1) * 64 + i * 16 + c16;
    b_off[i] = rb * 32 + ((quad ^ ((rb >> 1) & 3)) << 3);
  }
  auto stage = [&](int k0, int b) {
    const int o = b << 12;
    async16(Ah + gA0 + k0, Ahs + o + l0);
    async16(Ah + gA1 + k0, Ahs + o + l1);
    async16(Bh + gB0 + k0, Bhs + o + l0);
    async16(Bh + gB1 + k0, Bhs + o + l1);
    if constexpr (SPLIT2) {
      async16(Al + gA0 + k0, Als + o + l0);
      async16(Al + gA1 + k0, Als + o + l1);
      async16(Bl + gB0 + k0, Bls + o + l0);
      async16(Bl + gB1 + k0, Bls + o + l1);
    }
  };
  stage(0, 0);
  int cur = 0;
  for (int k0 = 0; k0 < K; k0 += 32, cur ^= 1) {
    __syncthreads();  // aged drain of buf[cur] prefetch
    if (k0 + 32 < K) stage(k0 + 32, cur ^ 1);
    const int o = cur << 12;
    f16x8 ah[4], bh[4];
#pragma unroll
    for (int i = 0; i < 4; i++) {
      ah[i] = *(const f16x8*)(Ahs + o + a_off[i]);
      bh[i] = *(const f16x8*)(Bhs + o + b_off[i]);
    }
    if constexpr (SPLIT2) {
      f16x8 al[4], bl[4];
#pragma unroll
      for (int i = 0; i < 4; i++) {
        al[i] = *(const f16x8*)(Als + o + a_off[i]);
        bl[i] = *(const f16x8*)(Bls + o + b_off[i]);
      }
#pragma unroll
      for (int i = 0; i < 4; i++)
#pragma unroll
        for (int j = 0; j < 4; j++) {
          acc[i][j] = __builtin_amdgcn_mfma_f32_16x16x32_f16(ah[i], bh[j], acc[i][j], 0, 0, 0);
          acc[i][j] = __builtin_amdgcn_mfma_f32_16x16x32_f16(ah[i], bl[j], acc[i][j], 0, 0, 0);
          acc[i][j] = __builtin_amdgcn_mfma_f32_16x16x32_f16(al[i], bh[j], acc[i][j], 0, 0, 0);
        }
    } else {
#pragma unroll
      for (int i = 0; i < 4; i++)
#pragma unroll
        for (int j = 0; j < 4; j++)
          acc[i][j] = __builtin_amdgcn_mfma_f32_16x16x32_f16(ah[i], bh[j], acc[i][j], 0, 0, 0);
    }
  }
}

// ---------------- QKV projection ----------------
// grid (32, 24): bx = m-tile (XCD-resident A slice), by = z*8 + n-tile
__global__ __launch_bounds__(256) void qkv_gemm(
    const f16* __restrict__ xh, const f16* __restrict__ xl,
    const f16* __restrict__ Wh, const f16* __restrict__ Wl,
    f16* __restrict__ Qh, f16* __restrict__ Ql, f16* __restrict__ Kh,
    f16* __restrict__ Kl, f16* __restrict__ Vt) {
  __shared__ __align__(16) f16 Ahs[2][4096], Als[2][4096], Bhs[2][4096],
      Bls[2][4096];
  const int z = blockIdx.y >> 3;
  const int m0 = blockIdx.x * 128, n0 = (blockIdx.y & 7) * 128;
  const f16* Bth = Wh + (size_t)z * E * E;
  const f16* Btl = Wl + (size_t)z * E * E;
  f32x4 acc[4][4];
  const f32x4 zero4 = {0.f, 0.f, 0.f, 0.f};
#pragma unroll
  for (int i = 0; i < 4; i++)
#pragma unroll
    for (int j = 0; j < 4; j++) acc[i][j] = zero4;
  if (z < 2)
    gemm_mainloop<true>(xh, xl, Bth, Btl, m0, n0, E, &Ahs[0][0], &Als[0][0],
                        &Bhs[0][0], &Bls[0][0], acc);
  else
    gemm_mainloop<false>(xh, nullptr, Bth, nullptr, m0, n0, E, &Ahs[0][0],
                         nullptr, &Bhs[0][0], nullptr, acc);
  const int tid = threadIdx.x, lane = tid & 63, wid = tid >> 6;
  const int quad = lane >> 4, c16 = lane & 15;
  if (z == 2) {
    // transpose wave's 64x64 tile through LDS, store Vt (B,H,D,S) coalesced
    __syncthreads();
    f16* vbuf = &Ahs[0][0] + (size_t)wid * 4608;  // 64 rows x 72 stride
#pragma unroll
    for (int i = 0; i < 4; i++)
#pragma unroll
      for (int j = 0; j < 4; j++)
#pragma unroll
        for (int r = 0; r < 4; r++) {
          int sl = i * 16 + quad * 4 + r;
          int dl = j * 16 + c16;
          vbuf[dl * 72 + sl] = (f16)acc[i][j][r];
        }
#pragma unroll
    for (int i2 = 0; i2 < 8; i2++) {
      int dl = i2 * 8 + (lane >> 3);
      int ck = lane & 7;
      f16x8 v8 = *(const f16x8*)(vbuf + dl * 72 + ck * 8);
      int dg = n0 + (wid & 1) * 64 + dl;
      int sg = m0 + (wid >> 1) * 64 + ck * 8;
      int b = sg >> 11, s = sg & (S - 1);
      int h = dg >> 6, d = dg & 63;
      *(f16x8*)(Vt + (((size_t)(b * NH + h) * HD + d) << 11) + s) = v8;
    }
  } else {
    // scalar split stores (low VGPR pressure beats b128 stores here)
    const float sc = 0.42466090014400953f;  // sqrt(0.125*log2(e))
#pragma unroll
    for (int i = 0; i < 4; i++)
#pragma unroll
      for (int j = 0; j < 4; j++)
#pragma unroll
        for (int r = 0; r < 4; r++) {
          int row = m0 + (wid >> 1) * 64 + i * 16 + quad * 4 + r;  // token
          int col = n0 + (wid & 1) * 64 + j * 16 + c16;            // embed idx
          int b = row >> 11, s = row & (S - 1);
          int h = col >> 6, d = col & 63;
          float v = acc[i][j][r] * sc;
          size_t idx = (((size_t)(b * NH + h) * S + s) << 6) + d;
          f16 hi = (f16)v;
          f16 lo = (f16)(v - (float)hi);
          if (z == 0) { Qh[idx] = hi; Ql[idx] = lo; }
          else        { Kh[idx] = hi; Kl[idx] = lo; }
        }
  }
}

// ---------------- flash attention (S^T orientation, 64-q-row blocks) ----------------
__global__ __launch_bounds__(256, 3) void flash(
    const f16* __restrict__ Qh, const f16* __restrict__ Ql,
    const f16* __restrict__ Kh, const f16* __restrict__ Kl,
    const f16* __restrict__ Vt, f16* __restrict__ Ao) {
  __shared__ __align__(16) f16 Khs[2][4096], Kls[2][4096], Vs[2][4096];
  const int tid = threadIdx.x, lane = tid & 63, wid = tid >> 6;
  const int quad = lane >> 4, c16 = lane & 15;
  // XCD swizzle: 4 bh per XCD, heavy q-tiles dispatched first
  const int flat = blockIdx.y * 32 + blockIdx.x;
  const int xcd = flat & 7, slot = flat >> 3;
  const int bh = xcd * 4 + (slot >> 5);
  const int qtile = 31 - (slot & 31);
  const int q0 = qtile * 64;
  const size_t bhoff = (size_t)bh * S * HD;
  const int qbase = wid * 16;
  f16x8 qf_h[2], qf_l[2];
#pragma unroll
  for (int ks = 0; ks < 2; ks++) {
    int q = q0 + qbase + c16;
    size_t off = bhoff + (size_t)q * HD + ks * 32 + quad * 8;
    qf_h[ks] = *(const f16x8*)(Qh + off);
    qf_l[ks] = *(const f16x8*)(Ql + off);
  }
  const int niter = qtile + 1;
  const int s0 = tid, s1 = 256 + tid;
  const int r0 = s0 >> 3, cc0 = ((s0 & 7) ^ (r0 & 7)) * 8;
  const int r1 = s1 >> 3, cc1 = ((s1 & 7) ^ (r1 & 7)) * 8;
  auto stage = [&](int it, int b) {
    const size_t kb = bhoff + (size_t)(it * 64) * HD;
    async16(Kh + kb + r0 * HD + cc0, &Khs[b][s0 * 8]);
    async16(Kh + kb + r1 * HD + cc1, &Khs[b][s1 * 8]);
    async16(Kl + kb + r0 * HD + cc0, &Kls[b][s0 * 8]);
    async16(Kl + kb + r1 * HD + cc1, &Kls[b][s1 * 8]);
    const size_t vb = bhoff + (size_t)(it * 64);
    async16(Vt + vb + (size_t)r0 * S + cc0, &Vs[b][s0 * 8]);
    async16(Vt + vb + (size_t)r1 * S + cc1, &Vs[b][s1 * 8]);
  };
  stage(0, 0);
  float mrow = -3.0e38f, lsum = 0.f;
  f32x4 oacc[4];  // O^T: row=quad*4+r -> d, col=c16 -> q
  const f32x4 zero4 = {0.f, 0.f, 0.f, 0.f};
#pragma unroll
  for (int dt = 0; dt < 4; dt++) oacc[dt] = zero4;
  const int qrow = q0 + qbase + c16;
  for (int it = 0; it < niter; ++it) {
    const int cur = it & 1;
    __syncthreads();  // drains prefetch of buf[cur]
    if (it + 1 < niter) stage(it + 1, cur ^ 1);
    const int k0 = it * 64;
    // --- S^T = K . Q^T ---
    f32x4 st[4];
#pragma unroll
    for (int kt = 0; kt < 4; kt++) st[kt] = zero4;
#pragma unroll
    for (int kt = 0; kt < 4; kt++) {
      int rowk = (kt * 16 + c16) * 64;
      int sx = c16 & 7;
      f16x8 kh0 = *(const f16x8*)&Khs[cur][rowk + ((quad ^ sx) << 3)];
      f16x8 kh1 = *(const f16x8*)&Khs[cur][rowk + (((4 + quad) ^ sx) << 3)];
      f16x8 kl0 = *(const f16x8*)&Kls[cur][rowk + ((quad ^ sx) << 3)];
      f16x8 kl1 = *(const f16x8*)&Kls[cur][rowk + (((4 + quad) ^ sx) << 3)];
      st[kt] = __builtin_amdgcn_mfma_f32_16x16x32_f16(kh0, qf_h[0], st[kt], 0, 0, 0);
      st[kt] = __builtin_amdgcn_mfma_f32_16x16x32_f16(kh1, qf_h[1], st[kt], 0, 0, 0);
      st[kt] = __builtin_amdgcn_mfma_f32_16x16x32_f16(kh0, qf_l[0], st[kt], 0, 0, 0);
      st[kt] = __builtin_amdgcn_mfma_f32_16x16x32_f16(kh1, qf_l[1], st[kt], 0, 0, 0);
      st[kt] = __builtin_amdgcn_mfma_f32_16x16x32_f16(kl0, qf_h[0], st[kt], 0, 0, 0);
      st[kt] = __builtin_amdgcn_mfma_f32_16x16x32_f16(kl1, qf_h[1], st[kt], 0, 0, 0);
    }
    // --- online softmax (logits already in exp2 units) ---
    if (it == niter - 1) {
#pragma unroll
      for (int kt = 0; kt < 4; kt++) {
        int kb = k0 + kt * 16 + quad * 4;
#pragma unroll
        for (int r = 0; r < 4; r++)
          if (kb + r > qrow) st[kt][r] = -3.0e38f;
      }
    }
    float mx = -3.0e38f;
#pragma unroll
    for (int kt = 0; kt < 4; kt++) {
      float a = fmaxf(fmaxf(st[kt][0], st[kt][1]), fmaxf(st[kt][2], st[kt][3]));
      mx = fmaxf(mx, a);
    }
    mx = fmaxf(mx, __shfl_xor(mx, 16, 64));
    mx = fmaxf(mx, __shfl_xor(mx, 32, 64));
    float mn = fmaxf(mrow, mx);
    float alpha = __builtin_amdgcn_exp2f(mrow - mn);
    mrow = mn;
    float ls = lsum * alpha;
    hv4 pb[4];
#pragma unroll
    for (int kt = 0; kt < 4; kt++) {
      float p0 = __builtin_amdgcn_exp2f(st[kt][0] - mn);
      float p1 = __builtin_amdgcn_exp2f(st[kt][1] - mn);
      float p2 = __builtin_amdgcn_exp2f(st[kt][2] - mn);
      float p3 = __builtin_amdgcn_exp2f(st[kt][3] - mn);
      ls += (p0 + p1) + (p2 + p3);
      hv4 pv = {(__fp16)p0, (__fp16)p1, (__fp16)p2, (__fp16)p3};
      pb[kt] = pv;
    }
    lsum = ls;
#pragma unroll
    for (int dt = 0; dt < 4; dt++) {
      oacc[dt][0] *= alpha;
      oacc[dt][1] *= alpha;
      oacc[dt][2] *= alpha;
      oacc[dt][3] *= alpha;
    }
    // --- O^T += V^T . P^T ---
#pragma unroll
    for (int kt = 0; kt < 4; kt++) {
#pragma unroll
      for (int dt = 0; dt < 4; dt++) {
        int rowd = dt * 16 + c16;
        int cidx = (kt * 2 + (quad >> 1)) ^ (rowd & 7);
        hv4 vf = *(const hv4*)&Vs[cur][rowd * 64 + (cidx << 3) + (quad & 1) * 4];
        oacc[dt] = __builtin_amdgcn_mfma_f32_16x16x16f16(vf, pb[kt], oacc[dt], 0, 0, 0);
      }
    }
  }
  // --- epilogue ---
  const int bb = bh >> 4, hh = bh & 15;
  float l = lsum;
  l += __shfl_xor(l, 16, 64);
  l += __shfl_xor(l, 32, 64);
  float iv = 1.0f / l;
  const int q = q0 + qbase + c16;
#pragma unroll
  for (int dt = 0; dt < 4; dt++) {
    f16x4 ov = {(f16)(oacc[dt][0] * iv), (f16)(oacc[dt][1] * iv),
                (f16)(oacc[dt][2] * iv), (f16)(oacc[dt][3] * iv)};
    *(f16x4*)(Ao + ((size_t)(bb * S + q)) * E + hh * 64 + dt * 16 + quad * 4) = ov;
  }
}

// ------------- output projection (64x128 tiles, dbuf, grid (64,8)) -------------
__global__ __launch_bounds__(256) void out_gemm(const f16* __restrict__ Ao,
                                                const f16* __restrict__ Wo,
                                                float* __restrict__ Cout) {
  __shared__ __align__(16) f16 Ahs[2][2048], Bhs[2][4096];
  const int tid = threadIdx.x, lane = tid & 63, wid = tid >> 6;
  const int quad = lane >> 4, c16 = lane & 15;
  const int m0 = blockIdx.x * 64, n0 = blockIdx.y * 128;
  f32x4 acc[4][2];
  const f32x4 zero4 = {0.f, 0.f, 0.f, 0.f};
#pragma unroll
  for (int i = 0; i < 4; i++)
#pragma unroll
    for (int j = 0; j < 2; j++) acc[i][j] = zero4;
  const int rA = tid >> 2;
  const int cA = (tid & 3) ^ ((rA >> 1) & 3);
  const size_t gA0 = (size_t)(m0 + rA) * E + cA * 8;
  const size_t gB0 = (size_t)(n0 + rA) * E + cA * 8;
  const size_t gB1 = (size_t)(n0 + 64 + rA) * E + cA * 8;
  const int l0 = tid * 8, l1 = (256 + tid) * 8;
  int a_off[4], b_off[2];
#pragma unroll
  for (int i = 0; i < 4; i++) {
    int ra = i * 16 + c16;
    a_off[i] = ra * 32 + ((quad ^ ((ra >> 1) & 3)) << 3);
  }
#pragma unroll
  for (int j = 0; j < 2; j++) {
    int rb = wid * 32 + j * 16 + c16;
    b_off[j] = rb * 32 + ((quad ^ ((rb >> 1) & 3)) << 3);
  }
  auto stage = [&](int k0, int b) {
    async16(Ao + gA0 + k0, &Ahs[b][0] + l0);
    async16(Wo + gB0 + k0, &Bhs[b][0] + l0);
    async16(Wo + gB1 + k0, &Bhs[b][0] + l1);
  };
  stage(0, 0);
  int cur = 0;
  for (int k0 = 0; k0 < E; k0 += 32, cur ^= 1) {
    __syncthreads();
    if (k0 + 32 < E) stage(k0 + 32, cur ^ 1);
    f16x8 ah[4], bh[2];
#pragma unroll
    for (int i = 0; i < 4; i++) ah[i] = *(const f16x8*)(&Ahs[cur][0] + a_off[i]);
#pragma unroll
    for (int j = 0; j < 2; j++) bh[j] = *(const f16x8*)(&Bhs[cur][0] + b_off[j]);
#pragma unroll
    for (int i = 0; i < 4; i++)
#pragma unroll
      for (int j = 0; j < 2; j++)
        acc[i][j] = __builtin_amdgcn_mfma_f32_16x16x32_f16(ah[i], bh[j], acc[i][j], 0, 0, 0);
  }
#pragma unroll
  for (int i = 0; i < 4; i++)
#pragma unroll
    for (int j = 0; j < 2; j++)
#pragma unroll
      for (int r = 0; r < 4; r++) {
        int row = m0 + i * 16 + quad * 4 + r;
        int col = n0 + wid * 32 + j * 16 + c16;
        Cout[(size_t)row * E + col] = acc[i][j][r];
      }
}

extern "C" void kernel_launch(void* const* d_in, const int* in_sizes, int n_in,
                              void* d_out, int out_size, void* d_ws,
                              size_t ws_size, hipStream_t stream) {
  const float* x = (const float*)d_in[0];
  const float* Wq = (const float*)d_in[1];
  const float* Wk = (const float*)d_in[2];
  const float* Wv = (const float*)d_in[3];
  const float* Wo = (const float*)d_in[4];
  char* ws = (char*)d_ws;
  const size_t MB = (size_t)1 << 20;
  f16* xh = (f16*)(ws + 0 * MB);
  f16* xl = (f16*)(ws + 8 * MB);
  f16* Wh = (f16*)(ws + 16 * MB);
  f16* Wl = (f16*)(ws + 24 * MB);
  f16* Qh = (f16*)(ws + 28 * MB);
  f16* Ql = (f16*)(ws + 36 * MB);
  f16* Kh = (f16*)(ws + 44 * MB);
  f16* Kl = (f16*)(ws + 52 * MB);
  f16* Vt = (f16*)(ws + 60 * MB);
  f16* Ao = (f16*)(ws + 68 * MB);
  cvt_all<<<dim3(32, 32, 5), 256, 0, stream>>>(x, Wq, Wk, Wv, Wo, xh, xl, Wh, Wl);
  qkv_gemm<<<dim3(32, 24), 256, 0, stream>>>(xh, xl, Wh, Wl, Qh, Ql, Kh, Kl, Vt);
  flash<<<dim3(32, 32), 256, 0, stream>>>(Qh, Ql, Kh, Kl, Vt, Ao);
  out_gemm<<<dim3(64, 8), 256, 0, stream>>>(Ao, Wh + (size_t)3 * E * E, (float*)d_out);
}